// Round 1
// baseline (96.885 us; speedup 1.0000x reference)
//
#include <hip/hip_runtime.h>

#define B_ 32
#define PRE_ 2048
#define POST_ 2048
#define QT 4             // q rows per WG in forward kernel
#define WPAD 2056        // LDS row stride (shorts); 2056*2B = 16B-multiple

// ws layout (unsigned short elements):
//   xrow [32][2048]   @ 0       x row-major bf16 (exact 0/1)    - forward A-frags
//   frag [2048][64]   @ 65536   per p: [ tp_bf16(32) | x_bf16(32) ] - dw B... (A) frags
//   spq  [2048][64]   @ 196608  per q: [ sp_bf16(32) | -tq_bf16(32) ]
#define XROW_OFF 0
#define FRAG_OFF 65536
#define SPQ_OFF  196608

typedef __attribute__((ext_vector_type(8))) short short8;
typedef __attribute__((ext_vector_type(4))) short short4v;
typedef __attribute__((ext_vector_type(4))) float floatx4;

__device__ __forceinline__ unsigned short f2bf(float f) {
    unsigned u = __float_as_uint(f);
    u += 0x7FFF + ((u >> 16) & 1);   // round-to-nearest-even
    return (unsigned short)(u >> 16);
}
__device__ __forceinline__ float bf2f(unsigned short h) {
    return __uint_as_float(((unsigned)h) << 16);
}

// K1: coalesced reads + LDS transpose (replaces the 4B column-strided reads).
// 256 WGs x 1 wave; WG owns an 8-wide p-tile for all 32 batch rows.
__global__ __launch_bounds__(64) void stdp_prep(
    const float* __restrict__ x, const float* __restrict__ tpre,
    unsigned short* __restrict__ ws)
{
    __shared__ __align__(16) unsigned short tt[8 * 80];  // [c 0..7][ tp b0..31 | x b0..31 ], pad 80
    const int lane = threadIdx.x;
    const int p0 = blockIdx.x * 8;
    const int b = lane >> 1, c4 = (lane & 1) * 4;

    floatx4 xv = *(const floatx4*)(x    + b * PRE_ + p0 + c4);
    floatx4 tv = *(const floatx4*)(tpre + b * PRE_ + p0 + c4);
    short4v xr;
#pragma unroll
    for (int j = 0; j < 4; ++j) {
        xr[j] = (short)(__float_as_uint(xv[j]) >> 16);            // exact for {0,1}
        tt[(c4 + j) * 80 + b]      = f2bf(0.5f * tv[j] + xv[j]);  // tp, rounded bf16
        tt[(c4 + j) * 80 + 32 + b] = (unsigned short)xr[j];
    }
    *(short4v*)(ws + XROW_OFF + b * PRE_ + p0 + c4) = xr;         // xrow, 8B store
    __syncthreads();
    // write frag rows p0..p0+7 fully coalesced (1KB contiguous per wave)
    const int pp = lane >> 3, seg = lane & 7;
    short8 v = *(const short8*)(tt + pp * 80 + seg * 8);
    *(short8*)(ws + FRAG_OFF + (p0 + pp) * 64 + seg * 8) = v;
}

// K2: forward only. QT=4 -> LDS 32.9KB (red aliases the dead Wh region after the
// forward barrier) -> 2 resident WGs/CU so W-load / convert / MFMA phases of
// different WGs overlap. Split-bf16 W for fp32-accurate spike threshold.
__global__ __launch_bounds__(512) void stdp_fwd(
    const float* __restrict__ W, const float* __restrict__ tpost,
    unsigned short* __restrict__ ws, float* __restrict__ out)
{
    __shared__ __align__(16) unsigned short sh[2 * QT * WPAD];   // 32.9 KB
    unsigned short* Wh = sh;
    unsigned short* Wl = sh + QT * WPAD;
    float* red = (float*)sh;   // 16 KB, aliases Wh (16448 B) after __syncthreads

    const int tid  = threadIdx.x;
    const int wave = tid >> 6, lane = tid & 63;
    const int quad = lane >> 4, l16 = lane & 15;
    const int q0   = blockIdx.x * QT;
    const int qb   = l16 & (QT - 1);
    const int kbase = wave * 256;     // wave's K-slice (wave-private LDS columns)

    float tpr[4];
    if (wave < 2 && l16 < QT) {
#pragma unroll
        for (int r = 0; r < 4; ++r)
            tpr[r] = tpost[(wave * 16 + quad * 4 + r) * POST_ + q0 + l16];
    }

    // stage W rows q0..q0+3, cols [kbase, kbase+256) as split bf16
    floatx4 wv[QT];
#pragma unroll
    for (int r = 0; r < QT; ++r)
        wv[r] = *(const floatx4*)(W + (q0 + r) * PRE_ + kbase + lane * 4);
#pragma unroll
    for (int r = 0; r < QT; ++r) {
        short4v hv, lv;
#pragma unroll
        for (int j = 0; j < 4; ++j) {
            unsigned short h = f2bf(wv[r][j]);
            hv[j] = (short)h;
            lv[j] = (short)f2bf(wv[r][j] - bf2f(h));
        }
        *(short4v*)&Wh[r * WPAD + kbase + lane * 4] = hv;
        *(short4v*)&Wl[r * WPAD + kbase + lane * 4] = lv;
    }

    // forward partial over this wave's K-slice (wave wrote exactly what it reads)
    const unsigned short* xrow = ws + XROW_OFF;
    floatx4 acc0 = {0.f, 0.f, 0.f, 0.f};
    floatx4 acc1 = {0.f, 0.f, 0.f, 0.f};
#pragma unroll
    for (int s = 0; s < 8; ++s) {
        int ko = kbase + s * 32 + quad * 8;
        short8 a0 = *(const short8*)(xrow + l16 * PRE_ + ko);
        short8 a1 = *(const short8*)(xrow + (16 + l16) * PRE_ + ko);
        short8 bh = *(const short8*)(Wh + qb * WPAD + ko);
        short8 bl = *(const short8*)(Wl + qb * WPAD + ko);
        acc0 = __builtin_amdgcn_mfma_f32_16x16x32_bf16(a0, bh, acc0, 0, 0, 0);
        acc0 = __builtin_amdgcn_mfma_f32_16x16x32_bf16(a0, bl, acc0, 0, 0, 0);
        acc1 = __builtin_amdgcn_mfma_f32_16x16x32_bf16(a1, bh, acc1, 0, 0, 0);
        acc1 = __builtin_amdgcn_mfma_f32_16x16x32_bf16(a1, bl, acc1, 0, 0, 0);
    }

    __syncthreads();                 // all waves done reading Wh/Wl
#pragma unroll
    for (int r = 0; r < 4; ++r) {
        red[((wave * 2 + 0) * 4 + r) * 64 + lane] = acc0[r];
        red[((wave * 2 + 1) * 4 + r) * 64 + lane] = acc1[r];
    }
    __syncthreads();

    if (wave < 2 && l16 < QT) {
        unsigned short* spq = ws + SPQ_OFF;
        int q = q0 + l16;
#pragma unroll
        for (int r = 0; r < 4; ++r) {
            float s = 0.f;
#pragma unroll
            for (int w = 0; w < 8; ++w) s += red[((w * 2 + wave) * 4 + r) * 64 + lane];
            int b = wave * 16 + quad * 4 + r;
            float spike = (s >= 1.0f) ? 1.0f : 0.0f;
            out[b * POST_ + q] = spike;
            float ntq = -(0.5f * tpr[r] + spike);     // -tq, single rounded bf16
            spq[q * 64 + b]      = f2bf(spike);
            spq[q * 64 + 32 + b] = f2bf(ntq);
        }
    }
}

// K3: dw. Zero LDS, 1024 WGs, 16 DISTINCT q per MFMA tile (no duplication).
// Operand order mfma(frag_p, spq_q) puts D-rows on p, so W-clamp load and dw
// store are one float4 per lane (16 complete 64B lines per store instr).
// W is L3-resident after K2; XCD swizzle gives each XCD a 2MB L2-resident W slice.
__global__ __launch_bounds__(256) void stdp_dw(
    const float* __restrict__ W, const unsigned short* __restrict__ ws,
    float* __restrict__ out)
{
    const unsigned short* frag = ws + FRAG_OFF;
    const unsigned short* spq  = ws + SPQ_OFF;
    float* dw = out + B_ * POST_;

    const int tid  = threadIdx.x;
    const int wave = tid >> 6, lane = tid & 63;
    const int quad = lane >> 4, l16 = lane & 15;
    // bijective XCD swizzle: 1024 blocks -> 8 contiguous 128-block chunks
    const int wid = (blockIdx.x & 7) * 128 + (blockIdx.x >> 3);
    const int gw  = wid * 4 + wave;          // 0..4095: (q-tile, p-strip)
    const int qt  = gw >> 5;                 // 0..127
    const int ps  = gw & 31;                 // 0..31
    const int q   = qt * 16 + l16;
    const int p0  = ps * 64;

    short8 fsp = *(const short8*)(spq + q * 64 + quad * 8);        // sp rows (B)
    short8 fnq = *(const short8*)(spq + q * 64 + 32 + quad * 8);   // -tq rows (B)

#pragma unroll
    for (int it = 0; it < 4; ++it) {
        int p = p0 + it * 16;
        short8 ftp = *(const short8*)(frag + (p + l16) * 64 + quad * 8);       // tp rows (A)
        short8 fx  = *(const short8*)(frag + (p + l16) * 64 + 32 + quad * 8);  // x rows (A)
        floatx4 acc = {0.f, 0.f, 0.f, 0.f};
        acc = __builtin_amdgcn_mfma_f32_16x16x32_bf16(ftp, fsp, acc, 0, 0, 0);
        acc = __builtin_amdgcn_mfma_f32_16x16x32_bf16(fx,  fnq, acc, 0, 0, 0);
        // acc[r] = D[row = quad*4+r (p-offset)][col = l16 (q)]
        floatx4 wq = *(const floatx4*)(W + q * PRE_ + p + quad * 4);
        floatx4 o;
#pragma unroll
        for (int r = 0; r < 4; ++r) {
            float wc = fminf(fmaxf(wq[r], -1.0f), 1.0f);
            o[r] = wc * acc[r];
        }
        *(floatx4*)(dw + q * PRE_ + p + quad * 4) = o;
    }
}

extern "C" void kernel_launch(void* const* d_in, const int* in_sizes, int n_in,
                              void* d_out, int out_size, void* d_ws, size_t ws_size,
                              hipStream_t stream) {
    const float* x     = (const float*)d_in[0];
    const float* W     = (const float*)d_in[1];
    const float* tpre  = (const float*)d_in[2];
    const float* tpost = (const float*)d_in[3];
    float* out = (float*)d_out;
    unsigned short* ws = (unsigned short*)d_ws;

    hipLaunchKernelGGL(stdp_prep, dim3(256), dim3(64), 0, stream, x, tpre, ws);
    hipLaunchKernelGGL(stdp_fwd,  dim3(POST_ / QT), dim3(512), 0, stream,
                       W, tpost, ws, out);
    hipLaunchKernelGGL(stdp_dw,   dim3(1024), dim3(256), 0, stream, W, ws, out);
}